// Round 3
// baseline (231.720 us; speedup 1.0000x reference)
//
#include <hip/hip_runtime.h>
#include <math.h>

// Kabsch RMSD, two-kernel structure.
//
// K1 (moments): B=4096 blocks x 256 threads, one row each. Thread t owns
// atoms {a*256 + t : a=0..7} as 12-byte float3 chunks -> every
// global_load_dwordx3 has a 12B lane stride = one contiguous 768B block per
// wave per instruction (12 fully-consumed cache lines; no L1 refetch).
// Accumulate 17 raw moments (Sx[3], Sy[3], S|x|^2, S|y|^2, M[9]) in f32,
// wave-shuffle + LDS reduce, write transposed to ws[k*B + row].
//
// K2 (eigensolve): one lane per row, coalesced moment reads, f64 closed-form
// 3x3 symmetric eigensolver on C^T C, writes rmsd.

#define NACC 17

struct F3 { float x, y, z; };   // 12 B, 4 B aligned -> global_load_dwordx3

__global__ __launch_bounds__(256, 8) void kabsch_moments_kernel(
    const float* __restrict__ X,   // B x 6144 f32
    const float* __restrict__ Y,   // B x 6144 f32
    const int* __restrict__ L,     // B
    float* __restrict__ WS,        // NACC x B (transposed)
    int B)
{
    const int row = blockIdx.x;
    const int tid = threadIdx.x;
    const int n = L[row] + 1;      // valid atom count

    const F3* __restrict__ Xr = (const F3*)(X + (size_t)row * 6144);
    const F3* __restrict__ Yr = (const F3*)(Y + (size_t)row * 6144);

    float v[NACC];
#pragma unroll
    for (int k = 0; k < NACC; ++k) v[k] = 0.0f;

    // two batches of 4 atoms to bound live registers (target <=64 VGPR)
#pragma unroll
    for (int batch = 0; batch < 2; ++batch) {
        F3 xa[4], ya[4];
        int atom[4];
#pragma unroll
        for (int i = 0; i < 4; ++i) {
            atom[i] = (batch * 4 + i) * 256 + tid;
            xa[i] = Xr[atom[i]];
        }
#pragma unroll
        for (int i = 0; i < 4; ++i) ya[i] = Yr[atom[i]];

#pragma unroll
        for (int i = 0; i < 4; ++i) {
            const float msk = (atom[i] < n) ? 1.0f : 0.0f;
            const float x0 = xa[i].x * msk;
            const float x1 = xa[i].y * msk;
            const float x2 = xa[i].z * msk;
            const float y0 = ya[i].x * msk;
            const float y1 = ya[i].y * msk;
            const float y2 = ya[i].z * msk;
            v[0] += x0; v[1] += x1; v[2] += x2;
            v[3] += y0; v[4] += y1; v[5] += y2;
            v[6] += x0 * x0 + x1 * x1 + x2 * x2;
            v[7] += y0 * y0 + y1 * y1 + y2 * y2;
            v[8]  += x0 * y0; v[9]  += x0 * y1; v[10] += x0 * y2;
            v[11] += x1 * y0; v[12] += x1 * y1; v[13] += x1 * y2;
            v[14] += x2 * y0; v[15] += x2 * y1; v[16] += x2 * y2;
        }
    }

    // wave-64 reduction
#pragma unroll
    for (int k = 0; k < NACC; ++k) {
        float t = v[k];
        t += __shfl_down(t, 32);
        t += __shfl_down(t, 16);
        t += __shfl_down(t, 8);
        t += __shfl_down(t, 4);
        t += __shfl_down(t, 2);
        t += __shfl_down(t, 1);
        v[k] = t;
    }

    __shared__ float red[4][NACC];
    const int wave = tid >> 6;
    const int lane = tid & 63;
    if (lane == 0) {
#pragma unroll
        for (int k = 0; k < NACC; ++k) red[wave][k] = v[k];
    }
    __syncthreads();

    if (tid < NACC) {
        const float s = red[0][tid] + red[1][tid] + red[2][tid] + red[3][tid];
        WS[(size_t)tid * B + row] = s;
    }
}

__global__ __launch_bounds__(64) void kabsch_eig_kernel(
    const float* __restrict__ WS,   // NACC x B
    const int* __restrict__ L,
    float* __restrict__ OUT,
    int B)
{
    const int row = blockIdx.x * 64 + threadIdx.x;
    if (row >= B) return;
    const int n = L[row] + 1;

    double s[NACC];
#pragma unroll
    for (int k = 0; k < NACC; ++k)
        s[k] = (double)WS[(size_t)k * B + row];

    const double inv_n = 1.0 / (double)n;
    const double sx0 = s[0], sx1 = s[1], sx2 = s[2];
    const double sy0 = s[3], sy1 = s[4], sy2 = s[5];
    const double ssq = s[6] + s[7]
        - (sx0 * sx0 + sx1 * sx1 + sx2 * sx2) * inv_n
        - (sy0 * sy0 + sy1 * sy1 + sy2 * sy2) * inv_n;

    double C[3][3];
    C[0][0] = s[8]  - sx0 * sy0 * inv_n;
    C[0][1] = s[9]  - sx0 * sy1 * inv_n;
    C[0][2] = s[10] - sx0 * sy2 * inv_n;
    C[1][0] = s[11] - sx1 * sy0 * inv_n;
    C[1][1] = s[12] - sx1 * sy1 * inv_n;
    C[1][2] = s[13] - sx1 * sy2 * inv_n;
    C[2][0] = s[14] - sx2 * sy0 * inv_n;
    C[2][1] = s[15] - sx2 * sy1 * inv_n;
    C[2][2] = s[16] - sx2 * sy2 * inv_n;

    const double det =
          C[0][0] * (C[1][1] * C[2][2] - C[1][2] * C[2][1])
        - C[0][1] * (C[1][0] * C[2][2] - C[1][2] * C[2][0])
        + C[0][2] * (C[1][0] * C[2][1] - C[1][1] * C[2][0]);

    // A = C^T C (symmetric PSD); eigenvalues = squared singular values
    double A[3][3];
#pragma unroll
    for (int i = 0; i < 3; ++i)
#pragma unroll
        for (int j = 0; j < 3; ++j)
            A[i][j] = C[0][i] * C[0][j] + C[1][i] * C[1][j] + C[2][i] * C[2][j];

    const double q  = (A[0][0] + A[1][1] + A[2][2]) / 3.0;
    const double p1 = A[0][1] * A[0][1] + A[0][2] * A[0][2] + A[1][2] * A[1][2];
    const double a00 = A[0][0] - q, a11 = A[1][1] - q, a22 = A[2][2] - q;
    const double p2 = a00 * a00 + a11 * a11 + a22 * a22 + 2.0 * p1;
    const double p  = sqrt(p2 / 6.0);

    double e1, e2, e3;
    if (p < 1e-30) {
        e1 = e2 = e3 = q;
    } else {
        const double ip = 1.0 / p;
        const double b00 = a00 * ip, b11 = a11 * ip, b22 = a22 * ip;
        const double b01 = A[0][1] * ip, b02 = A[0][2] * ip, b12 = A[1][2] * ip;
        double r = 0.5 * (b00 * (b11 * b22 - b12 * b12)
                        - b01 * (b01 * b22 - b12 * b02)
                        + b02 * (b01 * b12 - b11 * b02));
        r = fmin(1.0, fmax(-1.0, r));
        const double phi = acos(r) / 3.0;
        e1 = q + 2.0 * p * cos(phi);
        e3 = q + 2.0 * p * cos(phi + 2.0 * M_PI / 3.0);
        e2 = 3.0 * q - e1 - e3;
    }

    const double S0 = sqrt(fmax(e1, 0.0));
    const double S1 = sqrt(fmax(e2, 0.0));
    const double S2 = sqrt(fmax(e3, 0.0));
    const double d  = (det > 0.0) ? 1.0 : ((det < 0.0) ? -1.0 : 0.0);
    const double tr = S0 + S1 + d * S2;

    const double msd = fmax(ssq - 2.0 * tr, 0.0) * inv_n;
    OUT[row] = (float)sqrt(msd + 1e-12);
}

extern "C" void kernel_launch(void* const* d_in, const int* in_sizes, int n_in,
                              void* d_out, int out_size, void* d_ws, size_t ws_size,
                              hipStream_t stream) {
    const float* X = (const float*)d_in[0];
    const float* Y = (const float*)d_in[1];
    const int* L = (const int*)d_in[2];
    float* OUT = (float*)d_out;
    float* WS = (float*)d_ws;          // NACC * B floats

    const int B = in_sizes[2];         // 4096
    kabsch_moments_kernel<<<B, 256, 0, stream>>>(X, Y, L, WS, B);
    kabsch_eig_kernel<<<(B + 63) / 64, 64, 0, stream>>>(WS, L, OUT, B);
}

// Round 4
// 216.051 us; speedup vs baseline: 1.0725x; 1.0725x over previous
//
#include <hip/hip_runtime.h>
#include <math.h>

// Kabsch RMSD, two-kernel structure, LDS-staged.
//
// K1 (moments): one 256-thread block per row. The whole row (6144 floats x2
// arrays = 48 KB) is staged global->LDS via __builtin_amdgcn_global_load_lds
// (16 B/lane, lane-contiguous => every cache line fully consumed, deep async
// queue, no VGPR round-trip). Compute then reads per-atom float3 from LDS
// (12 B lane stride = 2-way bank aliasing = free). 17 raw moments in f32,
// wave-shuffle + LDS reduce, written transposed to ws[k*B + row].
//
// K2 (eigensolve): one lane per row, f64 closed-form 3x3 symmetric
// eigensolver on C^T C -> singular values -> rmsd.

#define NACC 17
#define ROWF 6144   // floats per row per array

typedef __attribute__((address_space(3))) void* as3_void;
typedef const __attribute__((address_space(1))) void* as1_cvoid;

__device__ __forceinline__ void g2lds16(const float* g, float* l) {
    // dest = lds_base + lane*16 (wave-uniform base); src = per-lane gptr
    __builtin_amdgcn_global_load_lds((as1_cvoid)g, (as3_void)l, 16, 0, 0);
}

__global__ __launch_bounds__(256) void kabsch_moments_kernel(
    const float* __restrict__ X,   // B x 6144 f32
    const float* __restrict__ Y,   // B x 6144 f32
    const int* __restrict__ L,     // B
    float* __restrict__ WS,        // NACC x B (transposed)
    int B)
{
    __shared__ __align__(16) float sX[ROWF];   // 24 KB
    __shared__ __align__(16) float sY[ROWF];   // 24 KB
    __shared__ float red[4][NACC];

    const int row = blockIdx.x;
    const int tid = threadIdx.x;
    const int lane = tid & 63;
    const int wave = tid >> 6;
    const int n = L[row] + 1;      // valid atom count

    const float* gX = X + (size_t)row * ROWF;
    const float* gY = Y + (size_t)row * ROWF;

    // Stage: each wave moves 256 floats (64 lanes x 16 B) per issue.
    // 6144 floats / (4 waves * 256) = 6 issues per array.
#pragma unroll
    for (int j = 0; j < 6; ++j) {
        const int off = (j * 4 + wave) * 256;          // wave-uniform
        g2lds16(gX + off + lane * 4, &sX[off]);
    }
#pragma unroll
    for (int j = 0; j < 6; ++j) {
        const int off = (j * 4 + wave) * 256;
        g2lds16(gY + off + lane * 4, &sY[off]);
    }
    __syncthreads();   // compiler emits s_waitcnt vmcnt(0) before s_barrier

    // accumulators: sx0..2, sy0..2, sxx, syy, m00..m22
    float v[NACC];
#pragma unroll
    for (int k = 0; k < NACC; ++k) v[k] = 0.0f;

#pragma unroll
    for (int a8 = 0; a8 < 8; ++a8) {
        const int atom = a8 * 256 + tid;
        const float msk = (atom < n) ? 1.0f : 0.0f;
        const float x0 = sX[3 * atom + 0] * msk;
        const float x1 = sX[3 * atom + 1] * msk;
        const float x2 = sX[3 * atom + 2] * msk;
        const float y0 = sY[3 * atom + 0] * msk;
        const float y1 = sY[3 * atom + 1] * msk;
        const float y2 = sY[3 * atom + 2] * msk;
        v[0] += x0; v[1] += x1; v[2] += x2;
        v[3] += y0; v[4] += y1; v[5] += y2;
        v[6] += x0 * x0 + x1 * x1 + x2 * x2;
        v[7] += y0 * y0 + y1 * y1 + y2 * y2;
        v[8]  += x0 * y0; v[9]  += x0 * y1; v[10] += x0 * y2;
        v[11] += x1 * y0; v[12] += x1 * y1; v[13] += x1 * y2;
        v[14] += x2 * y0; v[15] += x2 * y1; v[16] += x2 * y2;
    }

    // wave-64 reduction
#pragma unroll
    for (int k = 0; k < NACC; ++k) {
        float t = v[k];
        t += __shfl_down(t, 32);
        t += __shfl_down(t, 16);
        t += __shfl_down(t, 8);
        t += __shfl_down(t, 4);
        t += __shfl_down(t, 2);
        t += __shfl_down(t, 1);
        v[k] = t;
    }

    if (lane == 0) {
#pragma unroll
        for (int k = 0; k < NACC; ++k) red[wave][k] = v[k];
    }
    __syncthreads();

    if (tid < NACC) {
        const float s = red[0][tid] + red[1][tid] + red[2][tid] + red[3][tid];
        WS[(size_t)tid * B + row] = s;
    }
}

__global__ __launch_bounds__(64) void kabsch_eig_kernel(
    const float* __restrict__ WS,   // NACC x B
    const int* __restrict__ L,
    float* __restrict__ OUT,
    int B)
{
    const int row = blockIdx.x * 64 + threadIdx.x;
    if (row >= B) return;
    const int n = L[row] + 1;

    double s[NACC];
#pragma unroll
    for (int k = 0; k < NACC; ++k)
        s[k] = (double)WS[(size_t)k * B + row];

    const double inv_n = 1.0 / (double)n;
    const double sx0 = s[0], sx1 = s[1], sx2 = s[2];
    const double sy0 = s[3], sy1 = s[4], sy2 = s[5];
    const double ssq = s[6] + s[7]
        - (sx0 * sx0 + sx1 * sx1 + sx2 * sx2) * inv_n
        - (sy0 * sy0 + sy1 * sy1 + sy2 * sy2) * inv_n;

    double C[3][3];
    C[0][0] = s[8]  - sx0 * sy0 * inv_n;
    C[0][1] = s[9]  - sx0 * sy1 * inv_n;
    C[0][2] = s[10] - sx0 * sy2 * inv_n;
    C[1][0] = s[11] - sx1 * sy0 * inv_n;
    C[1][1] = s[12] - sx1 * sy1 * inv_n;
    C[1][2] = s[13] - sx1 * sy2 * inv_n;
    C[2][0] = s[14] - sx2 * sy0 * inv_n;
    C[2][1] = s[15] - sx2 * sy1 * inv_n;
    C[2][2] = s[16] - sx2 * sy2 * inv_n;

    const double det =
          C[0][0] * (C[1][1] * C[2][2] - C[1][2] * C[2][1])
        - C[0][1] * (C[1][0] * C[2][2] - C[1][2] * C[2][0])
        + C[0][2] * (C[1][0] * C[2][1] - C[1][1] * C[2][0]);

    // A = C^T C (symmetric PSD); eigenvalues = squared singular values
    double A[3][3];
#pragma unroll
    for (int i = 0; i < 3; ++i)
#pragma unroll
        for (int j = 0; j < 3; ++j)
            A[i][j] = C[0][i] * C[0][j] + C[1][i] * C[1][j] + C[2][i] * C[2][j];

    const double q  = (A[0][0] + A[1][1] + A[2][2]) / 3.0;
    const double p1 = A[0][1] * A[0][1] + A[0][2] * A[0][2] + A[1][2] * A[1][2];
    const double a00 = A[0][0] - q, a11 = A[1][1] - q, a22 = A[2][2] - q;
    const double p2 = a00 * a00 + a11 * a11 + a22 * a22 + 2.0 * p1;
    const double p  = sqrt(p2 / 6.0);

    double e1, e2, e3;
    if (p < 1e-30) {
        e1 = e2 = e3 = q;
    } else {
        const double ip = 1.0 / p;
        const double b00 = a00 * ip, b11 = a11 * ip, b22 = a22 * ip;
        const double b01 = A[0][1] * ip, b02 = A[0][2] * ip, b12 = A[1][2] * ip;
        double r = 0.5 * (b00 * (b11 * b22 - b12 * b12)
                        - b01 * (b01 * b22 - b12 * b02)
                        + b02 * (b01 * b12 - b11 * b02));
        r = fmin(1.0, fmax(-1.0, r));
        const double phi = acos(r) / 3.0;
        e1 = q + 2.0 * p * cos(phi);
        e3 = q + 2.0 * p * cos(phi + 2.0 * M_PI / 3.0);
        e2 = 3.0 * q - e1 - e3;
    }

    const double S0 = sqrt(fmax(e1, 0.0));
    const double S1 = sqrt(fmax(e2, 0.0));
    const double S2 = sqrt(fmax(e3, 0.0));
    const double d  = (det > 0.0) ? 1.0 : ((det < 0.0) ? -1.0 : 0.0);
    const double tr = S0 + S1 + d * S2;

    const double msd = fmax(ssq - 2.0 * tr, 0.0) * inv_n;
    OUT[row] = (float)sqrt(msd + 1e-12);
}

extern "C" void kernel_launch(void* const* d_in, const int* in_sizes, int n_in,
                              void* d_out, int out_size, void* d_ws, size_t ws_size,
                              hipStream_t stream) {
    const float* X = (const float*)d_in[0];
    const float* Y = (const float*)d_in[1];
    const int* L = (const int*)d_in[2];
    float* OUT = (float*)d_out;
    float* WS = (float*)d_ws;          // NACC * B floats

    const int B = in_sizes[2];         // 4096
    kabsch_moments_kernel<<<B, 256, 0, stream>>>(X, Y, L, WS, B);
    kabsch_eig_kernel<<<(B + 63) / 64, 64, 0, stream>>>(WS, L, OUT, B);
}

// Round 5
// 201.791 us; speedup vs baseline: 1.1483x; 1.0707x over previous
//
#include <hip/hip_runtime.h>
#include <math.h>

// Kabsch RMSD, two kernels.
//
// K1 (moments): ONE WAVE PER ROW, no LDS, no __syncthreads. 4096 waves
// (1024 blocks x 256 threads). Lane l owns floats [l*12, l*12+12) of each
// 768-float segment = exactly 4 atoms (components thread-local). Per row,
// only nIter = ceil(n/256) segments are processed -- atoms >= n contribute
// nothing, so ~half the loads are skipped on average (wave-uniform branch).
// Software-pipelined: prefetch segment it+1 while computing segment it.
// Wave-shuffle reduce of 17 f32 moments; lane 0 stores to WS[k*B+row].
//
// K2 (eigensolve): one lane per row, f64 closed-form 3x3 symmetric
// eigensolver on C^T C -> singular values -> rmsd.

#define NACC 17
#define ROWF 6144   // floats per row per array

__global__ __launch_bounds__(256) void kabsch_moments_kernel(
    const float* __restrict__ X,   // B x 6144 f32
    const float* __restrict__ Y,   // B x 6144 f32
    const int* __restrict__ L,     // B
    float* __restrict__ WS,        // NACC x B (transposed)
    int B)
{
    const int gwave = (int)((blockIdx.x * 256u + threadIdx.x) >> 6);
    const int lane  = threadIdx.x & 63;
    if (gwave >= B) return;
    const int row = gwave;
    const int n = L[row] + 1;              // valid atoms, 2..2047
    const int nIter = (n + 255) >> 8;      // segments of 256 atoms, 1..8

    const float* gX = X + (size_t)row * ROWF + (size_t)lane * 12;
    const float* gY = Y + (size_t)row * ROWF + (size_t)lane * 12;

    float v[NACC];
#pragma unroll
    for (int k = 0; k < NACC; ++k) v[k] = 0.0f;

    // prologue: load segment 0 (three float4 per array, 48 B lane stride)
    float4 cx0, cx1, cx2, cy0, cy1, cy2;
    {
        const float4* px = (const float4*)gX;
        const float4* py = (const float4*)gY;
        cx0 = px[0]; cx1 = px[1]; cx2 = px[2];
        cy0 = py[0]; cy1 = py[1]; cy2 = py[2];
    }

    for (int it = 0; it < nIter; ++it) {
        float4 nx0, nx1, nx2, ny0, ny1, ny2;
        const bool more = (it + 1 < nIter);
        if (more) {
            const float4* px = (const float4*)(gX + (it + 1) * 768);
            const float4* py = (const float4*)(gY + (it + 1) * 768);
            nx0 = px[0]; nx1 = px[1]; nx2 = px[2];
            ny0 = py[0]; ny1 = py[1]; ny2 = py[2];
        }

        float fx[12], fy[12];
        fx[0]=cx0.x; fx[1]=cx0.y; fx[2]=cx0.z; fx[3]=cx0.w;
        fx[4]=cx1.x; fx[5]=cx1.y; fx[6]=cx1.z; fx[7]=cx1.w;
        fx[8]=cx2.x; fx[9]=cx2.y; fx[10]=cx2.z; fx[11]=cx2.w;
        fy[0]=cy0.x; fy[1]=cy0.y; fy[2]=cy0.z; fy[3]=cy0.w;
        fy[4]=cy1.x; fy[5]=cy1.y; fy[6]=cy1.z; fy[7]=cy1.w;
        fy[8]=cy2.x; fy[9]=cy2.y; fy[10]=cy2.z; fy[11]=cy2.w;

        const int abase = it * 256 + lane * 4;
#pragma unroll
        for (int j = 0; j < 4; ++j) {
            const float msk = (abase + j < n) ? 1.0f : 0.0f;
            const float x0 = fx[3 * j + 0] * msk;
            const float x1 = fx[3 * j + 1] * msk;
            const float x2 = fx[3 * j + 2] * msk;
            const float y0 = fy[3 * j + 0] * msk;
            const float y1 = fy[3 * j + 1] * msk;
            const float y2 = fy[3 * j + 2] * msk;
            v[0] += x0; v[1] += x1; v[2] += x2;
            v[3] += y0; v[4] += y1; v[5] += y2;
            v[6] += x0 * x0 + x1 * x1 + x2 * x2;
            v[7] += y0 * y0 + y1 * y1 + y2 * y2;
            v[8]  += x0 * y0; v[9]  += x0 * y1; v[10] += x0 * y2;
            v[11] += x1 * y0; v[12] += x1 * y1; v[13] += x1 * y2;
            v[14] += x2 * y0; v[15] += x2 * y1; v[16] += x2 * y2;
        }

        if (more) {
            cx0 = nx0; cx1 = nx1; cx2 = nx2;
            cy0 = ny0; cy1 = ny1; cy2 = ny2;
        }
    }

    // wave-64 reduction (no LDS, no barrier)
#pragma unroll
    for (int k = 0; k < NACC; ++k) {
        float t = v[k];
        t += __shfl_down(t, 32);
        t += __shfl_down(t, 16);
        t += __shfl_down(t, 8);
        t += __shfl_down(t, 4);
        t += __shfl_down(t, 2);
        t += __shfl_down(t, 1);
        v[k] = t;
    }

    if (lane == 0) {
#pragma unroll
        for (int k = 0; k < NACC; ++k)
            WS[(size_t)k * B + row] = v[k];
    }
}

__global__ __launch_bounds__(256) void kabsch_eig_kernel(
    const float* __restrict__ WS,   // NACC x B
    const int* __restrict__ L,
    float* __restrict__ OUT,
    int B)
{
    const int row = blockIdx.x * 256 + threadIdx.x;
    if (row >= B) return;
    const int n = L[row] + 1;

    double s[NACC];
#pragma unroll
    for (int k = 0; k < NACC; ++k)
        s[k] = (double)WS[(size_t)k * B + row];

    const double inv_n = 1.0 / (double)n;
    const double sx0 = s[0], sx1 = s[1], sx2 = s[2];
    const double sy0 = s[3], sy1 = s[4], sy2 = s[5];
    const double ssq = s[6] + s[7]
        - (sx0 * sx0 + sx1 * sx1 + sx2 * sx2) * inv_n
        - (sy0 * sy0 + sy1 * sy1 + sy2 * sy2) * inv_n;

    double C[3][3];
    C[0][0] = s[8]  - sx0 * sy0 * inv_n;
    C[0][1] = s[9]  - sx0 * sy1 * inv_n;
    C[0][2] = s[10] - sx0 * sy2 * inv_n;
    C[1][0] = s[11] - sx1 * sy0 * inv_n;
    C[1][1] = s[12] - sx1 * sy1 * inv_n;
    C[1][2] = s[13] - sx1 * sy2 * inv_n;
    C[2][0] = s[14] - sx2 * sy0 * inv_n;
    C[2][1] = s[15] - sx2 * sy1 * inv_n;
    C[2][2] = s[16] - sx2 * sy2 * inv_n;

    const double det =
          C[0][0] * (C[1][1] * C[2][2] - C[1][2] * C[2][1])
        - C[0][1] * (C[1][0] * C[2][2] - C[1][2] * C[2][0])
        + C[0][2] * (C[1][0] * C[2][1] - C[1][1] * C[2][0]);

    // A = C^T C (symmetric PSD); eigenvalues = squared singular values
    double A[3][3];
#pragma unroll
    for (int i = 0; i < 3; ++i)
#pragma unroll
        for (int j = 0; j < 3; ++j)
            A[i][j] = C[0][i] * C[0][j] + C[1][i] * C[1][j] + C[2][i] * C[2][j];

    const double q  = (A[0][0] + A[1][1] + A[2][2]) / 3.0;
    const double p1 = A[0][1] * A[0][1] + A[0][2] * A[0][2] + A[1][2] * A[1][2];
    const double a00 = A[0][0] - q, a11 = A[1][1] - q, a22 = A[2][2] - q;
    const double p2 = a00 * a00 + a11 * a11 + a22 * a22 + 2.0 * p1;
    const double p  = sqrt(p2 / 6.0);

    double e1, e2, e3;
    if (p < 1e-30) {
        e1 = e2 = e3 = q;
    } else {
        const double ip = 1.0 / p;
        const double b00 = a00 * ip, b11 = a11 * ip, b22 = a22 * ip;
        const double b01 = A[0][1] * ip, b02 = A[0][2] * ip, b12 = A[1][2] * ip;
        double r = 0.5 * (b00 * (b11 * b22 - b12 * b12)
                        - b01 * (b01 * b22 - b12 * b02)
                        + b02 * (b01 * b12 - b11 * b02));
        r = fmin(1.0, fmax(-1.0, r));
        const double phi = acos(r) / 3.0;
        e1 = q + 2.0 * p * cos(phi);
        e3 = q + 2.0 * p * cos(phi + 2.0 * M_PI / 3.0);
        e2 = 3.0 * q - e1 - e3;
    }

    const double S0 = sqrt(fmax(e1, 0.0));
    const double S1 = sqrt(fmax(e2, 0.0));
    const double S2 = sqrt(fmax(e3, 0.0));
    const double d  = (det > 0.0) ? 1.0 : ((det < 0.0) ? -1.0 : 0.0);
    const double tr = S0 + S1 + d * S2;

    const double msd = fmax(ssq - 2.0 * tr, 0.0) * inv_n;
    OUT[row] = (float)sqrt(msd + 1e-12);
}

extern "C" void kernel_launch(void* const* d_in, const int* in_sizes, int n_in,
                              void* d_out, int out_size, void* d_ws, size_t ws_size,
                              hipStream_t stream) {
    const float* X = (const float*)d_in[0];
    const float* Y = (const float*)d_in[1];
    const int* L = (const int*)d_in[2];
    float* OUT = (float*)d_out;
    float* WS = (float*)d_ws;              // NACC * B floats

    const int B = in_sizes[2];             // 4096
    const int waves_blocks = (B * 64 + 255) / 256;   // one wave per row
    kabsch_moments_kernel<<<waves_blocks, 256, 0, stream>>>(X, Y, L, WS, B);
    kabsch_eig_kernel<<<(B + 255) / 256, 256, 0, stream>>>(WS, L, OUT, B);
}